// Round 8
// baseline (416.151 us; speedup 1.0000x reference)
//
#include <hip/hip_runtime.h>
#include <hip/hip_bf16.h>
#include <math.h>

#define B_   32
#define T_   4096
#define D_   1024
#define H_   256
#define KTH  2048           // threshold_index = int(T*0.5)
#define SC   64             // pv chunks per batch
#define BM   128
#define BKE  32
#define NTE  (D_/BKE)       // 32 k-steps
#define ASZ  (BM*BKE)       // 4096 ushorts per A buf (8 KB)
#define BSZ  (H_*BKE)       // 8192 ushorts per B buf (16 KB)
#define EPSB 4.0e-3f        // refinement band half-width (~8 sigma of bf16 e-error)
#define MAXBAND 256
#define RB   4              // refine rows per block-group

typedef __attribute__((ext_vector_type(8))) short short8;
typedef __attribute__((ext_vector_type(4))) float f32x4;

#define FENCE3() asm volatile("s_waitcnt vmcnt(3) lgkmcnt(0)" ::: "memory")
#define FENCE0() asm volatile("s_waitcnt vmcnt(0) lgkmcnt(0)" ::: "memory")
#define BARRIER() __builtin_amdgcn_s_barrier()
#define GLL(src, dst) __builtin_amdgcn_global_load_lds( \
    (const __attribute__((address_space(1))) unsigned int*)(src), \
    (__attribute__((address_space(3))) unsigned int*)(dst), 16, 0, 0)

// ---------- helpers ----------
__device__ inline unsigned f2s(float f) {
    unsigned u = __float_as_uint(f);
    return (u & 0x80000000u) ? ~u : (u | 0x80000000u);
}
__device__ inline float s2f(unsigned s) {
    unsigned x = (s & 0x80000000u) ? (s & 0x7fffffffu) : ~s;
    return __uint_as_float(x);
}
__device__ inline unsigned f2bf_rne(float f) {      // round-to-nearest-even bf16
    unsigned u = __float_as_uint(f);
    return (u + 0x7FFFu + ((u >> 16) & 1u)) >> 16;
}
__device__ inline unsigned pk2(float a, float b) {
    return f2bf_rne(a) | (f2bf_rne(b) << 16);
}
__device__ inline float bf2f(ushort u) {
    return __uint_as_float(((unsigned)u) << 16);
}
__device__ inline int block_sum_i(int v, int* sb, int tid) {
    #pragma unroll
    for (int o = 32; o; o >>= 1) v += __shfl_down(v, o);
    __syncthreads();
    if ((tid & 63) == 0) sb[tid >> 6] = v;
    __syncthreads();
    return sb[0] + sb[1] + sb[2] + sb[3];
}
__device__ inline float block_max_f(float v, float* sb, int tid) {
    #pragma unroll
    for (int o = 32; o; o >>= 1) v = fmaxf(v, __shfl_down(v, o));
    __syncthreads();
    if ((tid & 63) == 0) sb[tid >> 6] = v;
    __syncthreads();
    return fmaxf(fmaxf(sb[0], sb[1]), fmaxf(sb[2], sb[3]));
}
__device__ inline float block_sum_f(float v, float* sb, int tid) {
    #pragma unroll
    for (int o = 32; o; o >>= 1) v += __shfl_down(v, o);
    __syncthreads();
    if ((tid & 63) == 0) sb[tid >> 6] = v;
    __syncthreads();
    return sb[0] + sb[1] + sb[2] + sb[3];
}

// ---------- phase 0a: x fp32 -> bf16(RNE), pure streaming ----------
__global__ __launch_bounds__(256) void k_cvt(const float* __restrict__ x,
                                             ushort* __restrict__ xb) {
    const long n = (long)B_ * T_ * D_;
    const long stride = (long)gridDim.x * 256 * 8;
    for (long i = ((long)blockIdx.x * 256 + threadIdx.x) * 8; i < n; i += stride) {
        float4 a = *(const float4*)(x + i);
        float4 b = *(const float4*)(x + i + 4);
        uint4 p = make_uint4(pk2(a.x, a.y), pk2(a.z, a.w),
                             pk2(b.x, b.y), pk2(b.z, b.w));
        *(uint4*)(xb + i) = p;
    }
}

// ---------- phase 0b: W1 [K][N] fp32 -> W1T bf16(RNE) [N][K] ----------
__global__ __launch_bounds__(256) void k_w1t(const float* __restrict__ W1,
                                             ushort* __restrict__ Whi) {
    __shared__ float tile[32][33];
    const int kb = blockIdx.x * 32, nb = blockIdx.y * 32;
    const int tx = threadIdx.x & 31, ty = threadIdx.x >> 5;   // ty 0..7
    #pragma unroll
    for (int i = 0; i < 4; i++)
        tile[ty + 8*i][tx] = W1[(long)(kb + ty + 8*i) * H_ + nb + tx];
    __syncthreads();
    #pragma unroll
    for (int i = 0; i < 4; i++) {
        long o = (long)(nb + ty + 8*i) * D_ + kb + tx;
        Whi[o] = (ushort)f2bf_rne(tile[tx][ty + 8*i]);
    }
}

// ---------- phase 1: all-gload_lds bf16 MFMA GEMM + tanh/W2 epilogue -> e ----------
// 512 thr = 8 waves (2m x 4n), block tile 128x256, BK=32, triple-buffered.
// Per k-step per thread: 1 A gload_lds + 2 B gload_lds (16B each). Counted
// fence vmcnt(3)+lgkmcnt(0) per step (depth-2 pipeline, never vmcnt(0) in loop).
// LDS fragment-major: [slab=row>>4][kchunk][row&15][8] -> frag ds_read_b128
// at base+lane*16, conflict-free. No cvt, no reg staging -> ~110 VGPR.
__global__ __launch_bounds__(512, 4) void k_e_mfma(
    const ushort* __restrict__ xb,
    const ushort* __restrict__ Whi,
    const float* __restrict__ b1, const float* __restrict__ W2,
    const float* __restrict__ b2, float* __restrict__ e_out)
{
    __shared__ ushort sA[3 * ASZ];   // 24 KB
    __shared__ ushort sB[3 * BSZ];   // 48 KB
    __shared__ float  sRed[4][BM];   // 2 KB

    const int tid  = threadIdx.x;
    const int lane = tid & 63;
    const int wv   = tid >> 6;
    const int wm   = wv >> 2, wn = wv & 3;
    const int l15  = lane & 15, lg = lane >> 4;
    const long row0 = (long)blockIdx.x * BM;

    // A staging: chunk c=tid (512 chunks): row=(c>>6)*16+(c&15), kc=(c>>4)&3
    const int arow = (tid >> 6) * 16 + (tid & 15);
    const int akc  = (tid >> 4) & 3;
    const ushort* asrc = xb + (row0 + arow) * (long)D_ + akc * 8;
    const int adst = tid * 8;                        // ushort idx (16B/chunk)

    // B staging: chunks c=tid, tid+512: n=(c>>6)*16+(c&15), kc=(c>>4)&3
    const int c1 = tid + 512;
    const int bn0 = (tid >> 6) * 16 + (tid & 15), bk0 = (tid >> 4) & 3;
    const int bn1 = (c1 >> 6) * 16 + (c1 & 15),  bk1 = (c1 >> 4) & 3;
    const ushort* bsrc0 = Whi + (long)bn0 * D_ + bk0 * 8;
    const ushort* bsrc1 = Whi + (long)bn1 * D_ + bk1 * 8;
    const int bdst0 = tid * 8, bdst1 = c1 * 8;

    // fragment read offsets (lane-linear by construction)
    int aoff[4], boff[4];
    #pragma unroll
    for (int fm = 0; fm < 4; fm++)
        aoff[fm] = (wm * 4 + fm) * 512 + lg * 128 + l15 * 8;
    #pragma unroll
    for (int fn = 0; fn < 4; fn++)
        boff[fn] = (wn * 4 + fn) * 512 + lg * 128 + l15 * 8;

    f32x4 acc[4][4];
    #pragma unroll
    for (int i = 0; i < 4; i++)
        #pragma unroll
        for (int j = 0; j < 4; j++) acc[i][j] = (f32x4){0.f, 0.f, 0.f, 0.f};

    auto stage = [&](int t, int bi) {
        const int ko = t * BKE;
        GLL(asrc + ko,  sA + bi * ASZ + adst);
        GLL(bsrc0 + ko, sB + bi * BSZ + bdst0);
        GLL(bsrc1 + ko, sB + bi * BSZ + bdst1);
    };
    auto compute = [&](int bi) {
        const ushort* sa = sA + bi * ASZ;
        const ushort* sb = sB + bi * BSZ;
        short8 bfr[4];
        #pragma unroll
        for (int fn = 0; fn < 4; fn++)
            bfr[fn] = *(const short8*)&sb[boff[fn]];
        __builtin_amdgcn_s_setprio(1);
        #pragma unroll
        for (int fm = 0; fm < 4; fm++) {
            short8 afr = *(const short8*)&sa[aoff[fm]];
            #pragma unroll
            for (int fn = 0; fn < 4; fn++)
                acc[fm][fn] = __builtin_amdgcn_mfma_f32_16x16x32_bf16(afr, bfr[fn], acc[fm][fn], 0, 0, 0);
        }
        __builtin_amdgcn_s_setprio(0);
    };

    // prologue: tiles 0,1 in flight
    stage(0, 0);
    stage(1, 1);

    int bi = 0;
    for (int t = 0; t <= NTE - 3; ++t) {
        FENCE3(); BARRIER();
        const int nb = (bi + 2 >= 3) ? bi - 1 : bi + 2;
        stage(t + 2, nb);
        compute(bi);
        bi = (bi + 1 == 3) ? 0 : bi + 1;
    }
    // t = NTE-2: nothing left to stage
    FENCE3(); BARRIER();
    compute(bi);
    bi = (bi + 1 == 3) ? 0 : bi + 1;
    // t = NTE-1: final drain
    FENCE0(); BARRIER();
    compute(bi);

    // epilogue: e partial = sum_j tanh(G+b1[j])*W2[j]; D frag: col=l15, row=lg*4+r
    float b1v[4], w2v[4];
    #pragma unroll
    for (int fn = 0; fn < 4; fn++) {
        int j = wn * 64 + fn * 16 + l15;
        b1v[fn] = b1[j]; w2v[fn] = W2[j];
    }
    #pragma unroll
    for (int fm = 0; fm < 4; fm++) {
        #pragma unroll
        for (int r = 0; r < 4; r++) {
            float s = 0.f;
            #pragma unroll
            for (int fn = 0; fn < 4; fn++)
                s += tanhf(acc[fm][fn][r] + b1v[fn]) * w2v[fn];
            s += __shfl_xor(s, 1); s += __shfl_xor(s, 2);
            s += __shfl_xor(s, 4); s += __shfl_xor(s, 8);
            if (l15 == 0) sRed[wn][wm * 64 + fm * 16 + lg * 4 + r] = s;
        }
    }
    __syncthreads();
    if (tid < BM)
        e_out[row0 + tid] = sRed[0][tid] + sRed[1][tid] + sRed[2][tid] + sRed[3][tid] + b2[0];
}

// ---------- phase 2: rank threshold; BUILD=1 -> band list, BUILD=0 -> survivor list ----------
// thread handles 16 CONSECUTIVE t (t = tid*16+i) so compaction is t-ordered.
template<int BUILD>
__global__ __launch_bounds__(256) void k_thresh(const float* __restrict__ e,
                                                int* __restrict__ counts,
                                                int* __restrict__ list,
                                                int* __restrict__ sidx,
                                                float* __restrict__ sval,
                                                int* __restrict__ scount) {
    __shared__ int   sbi[4];
    __shared__ float sbf[4];
    __shared__ int   wsum[4];
    __shared__ int   scnt;
    const int b = blockIdx.x, tid = threadIdx.x;
    const int lane = tid & 63, wid = tid >> 6;
    const float* eb = e + (long)b * T_;
    const int t0 = tid * 16;

    float fe[16]; unsigned ue[16];
    #pragma unroll
    for (int i = 0; i < 16; i += 4) {
        float4 v = *(const float4*)(eb + t0 + i);
        fe[i] = v.x; fe[i+1] = v.y; fe[i+2] = v.z; fe[i+3] = v.w;
    }
    #pragma unroll
    for (int i = 0; i < 16; i++) ue[i] = f2s(fe[i]);

    unsigned lo = 0u, hi = 0xFFFFFFFFu;
    while (lo < hi) {
        unsigned mid = lo + ((hi - lo) >> 1);
        int c = 0;
        #pragma unroll
        for (int i = 0; i < 16; i++) c += (ue[i] <= mid) ? 1 : 0;
        int total = block_sum_i(c, sbi, tid);
        if (total >= KTH + 1) hi = mid; else lo = mid + 1;
    }
    const float thr = s2f(lo);

    if (BUILD) {
        if (tid == 0) scnt = 0;
        __syncthreads();
        #pragma unroll
        for (int i = 0; i < 16; i++) {
            if (fabsf(fe[i] - thr) <= EPSB) {
                int p = atomicAdd(&scnt, 1);
                if (p < MAXBAND) list[b * MAXBAND + p] = t0 + i;
            }
        }
        __syncthreads();
        if (tid == 0) counts[b] = scnt < MAXBAND ? scnt : MAXBAND;
    } else {
        float m = -INFINITY;
        #pragma unroll
        for (int i = 0; i < 16; i++) if (fe[i] < thr) m = fmaxf(m, fe[i]);
        m = block_max_f(m, sbf, tid);
        float s = 0.f;
        #pragma unroll
        for (int i = 0; i < 16; i++) if (fe[i] < thr) s += expf(fe[i] - m);
        s = block_sum_f(s, sbf, tid);
        const float inv = 1.0f / s;

        // deterministic t-ordered compaction: block exclusive scan of counts
        int c = 0;
        #pragma unroll
        for (int i = 0; i < 16; i++) c += (fe[i] < thr) ? 1 : 0;
        int p = c;
        #pragma unroll
        for (int o = 1; o < 64; o <<= 1) {
            int y = __shfl_up(p, o);
            if (lane >= o) p += y;
        }
        if (lane == 63) wsum[wid] = p;          // wave total
        __syncthreads();
        int base = 0;
        #pragma unroll
        for (int w = 0; w < 4; w++) base += (w < wid) ? wsum[w] : 0;
        int pos = base + p - c;                 // exclusive prefix
        #pragma unroll
        for (int i = 0; i < 16; i++) {
            if (fe[i] < thr) {
                sidx[(long)b * T_ + pos] = t0 + i;
                sval[(long)b * T_ + pos] = expf(fe[i] - m) * inv;
                pos++;
            }
        }
        if (tid == 0) scount[b] = wsum[0] + wsum[1] + wsum[2] + wsum[3];
    }
}

// ---------- phase 2.5: exact fp32 recompute of band rows, RB rows share one W1 stream ----------
__global__ __launch_bounds__(256) void k_refine(const float* __restrict__ x,
        const float* __restrict__ W1, const float* __restrict__ b1,
        const float* __restrict__ W2, const float* __restrict__ b2,
        const int* __restrict__ counts, const int* __restrict__ list,
        float* __restrict__ e) {
    const int b   = blockIdx.y;
    const int blk = blockIdx.x;            // 0..15
    const int cnt = counts[b];
    const int tid = threadIdx.x;
    __shared__ float xs[RB][D_];           // 16 KB
    __shared__ float sbf[4];

    for (int g = blk * RB; g < cnt; g += 16 * RB) {
        const int nr = min(RB, cnt - g);
        for (int j = 0; j < nr; j++) {
            const int t = list[b * MAXBAND + g + j];
            *(float4*)&xs[j][tid * 4] =
                *(const float4*)&x[((long)b * T_ + t) * D_ + tid * 4];
        }
        __syncthreads();

        float a0 = 0.f, a1 = 0.f, a2 = 0.f, a3 = 0.f;
        for (int k0 = 0; k0 < D_; k0 += 4) {
            const float w0 = W1[(long)(k0 + 0) * H_ + tid];
            const float w1v = W1[(long)(k0 + 1) * H_ + tid];
            const float w2q = W1[(long)(k0 + 2) * H_ + tid];
            const float w3 = W1[(long)(k0 + 3) * H_ + tid];
            {
                float4 xv = *(const float4*)&xs[0][k0];
                a0 = fmaf(xv.x, w0, a0); a0 = fmaf(xv.y, w1v, a0);
                a0 = fmaf(xv.z, w2q, a0); a0 = fmaf(xv.w, w3, a0);
            }
            {
                float4 xv = *(const float4*)&xs[1][k0];
                a1 = fmaf(xv.x, w0, a1); a1 = fmaf(xv.y, w1v, a1);
                a1 = fmaf(xv.z, w2q, a1); a1 = fmaf(xv.w, w3, a1);
            }
            {
                float4 xv = *(const float4*)&xs[2][k0];
                a2 = fmaf(xv.x, w0, a2); a2 = fmaf(xv.y, w1v, a2);
                a2 = fmaf(xv.z, w2q, a2); a2 = fmaf(xv.w, w3, a2);
            }
            {
                float4 xv = *(const float4*)&xs[3][k0];
                a3 = fmaf(xv.x, w0, a3); a3 = fmaf(xv.y, w1v, a3);
                a3 = fmaf(xv.z, w2q, a3); a3 = fmaf(xv.w, w3, a3);
            }
        }

        float aj[RB] = {a0, a1, a2, a3};
        for (int j = 0; j < nr; j++) {
            float v = tanhf(aj[j] + b1[tid]) * W2[tid];
            float tot = block_sum_f(v, sbf, tid);
            if (tid == 0) {
                const int t = list[b * MAXBAND + g + j];
                e[(long)b * T_ + t] = tot + b2[0];
            }
            __syncthreads();
        }
        __syncthreads();
    }
}

// ---------- phase 3: dense survivor-list PV over bf16 x ----------
__global__ __launch_bounds__(256) void k_pv(const ushort* __restrict__ xb,
                                            const int* __restrict__ sidx,
                                            const float* __restrict__ sval,
                                            const int* __restrict__ scount,
                                            float* __restrict__ partial) {
    const int c = blockIdx.x, b = blockIdx.y, tid = threadIdx.x;
    const int cnt = scount[b];
    const int len = (cnt + SC - 1) / SC;       // <= 32 (cnt <= 2048)
    const int k0 = c * len;
    const int nl = min(len, cnt - k0);
    __shared__ int   si[32];
    __shared__ float sv[32];
    if (tid < nl) {
        si[tid] = sidx[(long)b * T_ + k0 + tid];
        sv[tid] = sval[(long)b * T_ + k0 + tid];
    }
    __syncthreads();

    float4 acc = {0.f, 0.f, 0.f, 0.f};
    const ushort* xbb = xb + (long)b * T_ * D_ + tid * 4;
    #pragma unroll 4
    for (int k = 0; k < nl; k++) {
        const float w = sv[k];
        ushort4 v = *(const ushort4*)(xbb + (long)si[k] * D_);
        acc.x = fmaf(w, bf2f(v.x), acc.x);
        acc.y = fmaf(w, bf2f(v.y), acc.y);
        acc.z = fmaf(w, bf2f(v.z), acc.z);
        acc.w = fmaf(w, bf2f(v.w), acc.w);
    }
    *(float4*)&partial[(((long)b * SC) + c) * D_ + tid * 4] = acc;
}

// ---------- phase 4 ----------
__global__ __launch_bounds__(256) void k_red(const float* __restrict__ partial,
                                             float* __restrict__ out) {
    const int b = blockIdx.x, tid = threadIdx.x;
    float4 acc = {0.f, 0.f, 0.f, 0.f};
    #pragma unroll
    for (int c = 0; c < SC; c++) {
        float4 v = *(const float4*)&partial[(((long)b * SC) + c) * D_ + tid * 4];
        acc.x += v.x; acc.y += v.y; acc.z += v.z; acc.w += v.w;
    }
    *(float4*)&out[(long)b * D_ + tid * 4] = acc;
}

extern "C" void kernel_launch(void* const* d_in, const int* in_sizes, int n_in,
                              void* d_out, int out_size, void* d_ws, size_t ws_size,
                              hipStream_t stream) {
    const float* x  = (const float*)d_in[0];
    const float* W1 = (const float*)d_in[1];
    const float* b1 = (const float*)d_in[2];
    const float* W2 = (const float*)d_in[3];
    const float* b2 = (const float*)d_in[4];
    float* out = (float*)d_out;

    char* ws = (char*)d_ws;
    float* e       = (float*)ws;  ws += (size_t)B_ * T_ * 4;
    int*   sidx    = (int*)ws;    ws += (size_t)B_ * T_ * 4;
    float* sval    = (float*)ws;  ws += (size_t)B_ * T_ * 4;
    float* partial = (float*)ws;  ws += (size_t)B_ * SC * D_ * 4;
    ushort* Whi    = (ushort*)ws; ws += (size_t)H_ * D_ * 2;
    int* counts    = (int*)ws;    ws += 128;
    int* scountp   = (int*)ws;    ws += 128;
    int* list      = (int*)ws;    ws += (size_t)B_ * MAXBAND * 4;
    ushort* xb16   = (ushort*)(((uintptr_t)ws + 255) & ~(uintptr_t)255);

    k_cvt<<<2048, 256, 0, stream>>>(x, xb16);
    k_w1t<<<dim3(D_ / 32, H_ / 32), 256, 0, stream>>>(W1, Whi);
    k_e_mfma<<<(B_ * T_) / BM, 512, 0, stream>>>(xb16, Whi, b1, W2, b2, e);
    k_thresh<1><<<B_, 256, 0, stream>>>(e, counts, list, sidx, sval, scountp);
    k_refine<<<dim3(16, B_), 256, 0, stream>>>(x, W1, b1, W2, b2, counts, list, e);
    k_thresh<0><<<B_, 256, 0, stream>>>(e, counts, list, sidx, sval, scountp);
    k_pv<<<dim3(SC, B_), 256, 0, stream>>>(xb16, sidx, sval, scountp, partial);
    k_red<<<B_, 256, 0, stream>>>(partial, out);
}

// Round 9
// 392.088 us; speedup vs baseline: 1.0614x; 1.0614x over previous
//
#include <hip/hip_runtime.h>
#include <hip/hip_bf16.h>
#include <math.h>

#define B_   32
#define T_   4096
#define D_   1024
#define H_   256
#define KTH  2048           // threshold_index = int(T*0.5)
#define SC   64             // pv chunks per batch
#define BM   128
#define BKL  64             // K per tile
#define NKT  (D_/BKL)       // 16 K-tiles
#define EPSB 4.0e-3f        // refinement band half-width (~8 sigma of bf16 e-error)
#define MAXBAND 256
#define RB   4              // refine rows per block-group

typedef __attribute__((ext_vector_type(8))) short short8;
typedef __attribute__((ext_vector_type(4))) float f32x4;

#define FENCEA() asm volatile("s_waitcnt vmcnt(4) lgkmcnt(0)" ::: "memory")
#define FENCE0() asm volatile("s_waitcnt vmcnt(0) lgkmcnt(0)" ::: "memory")
#define LGKM0()  asm volatile("s_waitcnt lgkmcnt(0)" ::: "memory")
#define BARRIER() __builtin_amdgcn_s_barrier()
#define GLL(src, dst) __builtin_amdgcn_global_load_lds( \
    (const __attribute__((address_space(1))) unsigned int*)(src), \
    (__attribute__((address_space(3))) unsigned int*)(dst), 16, 0, 0)

// ---------- helpers ----------
__device__ inline unsigned f2s(float f) {
    unsigned u = __float_as_uint(f);
    return (u & 0x80000000u) ? ~u : (u | 0x80000000u);
}
__device__ inline float s2f(unsigned s) {
    unsigned x = (s & 0x80000000u) ? (s & 0x7fffffffu) : ~s;
    return __uint_as_float(x);
}
__device__ inline unsigned f2bf_rne(float f) {      // round-to-nearest-even bf16
    unsigned u = __float_as_uint(f);
    return (u + 0x7FFFu + ((u >> 16) & 1u)) >> 16;
}
__device__ inline unsigned pk2(float a, float b) {
    return f2bf_rne(a) | (f2bf_rne(b) << 16);
}
__device__ inline float bf2f(ushort u) {
    return __uint_as_float(((unsigned)u) << 16);
}
__device__ inline int block_sum_i(int v, int* sb, int tid) {
    #pragma unroll
    for (int o = 32; o; o >>= 1) v += __shfl_down(v, o);
    __syncthreads();
    if ((tid & 63) == 0) sb[tid >> 6] = v;
    __syncthreads();
    return sb[0] + sb[1] + sb[2] + sb[3];
}
__device__ inline float block_max_f(float v, float* sb, int tid) {
    #pragma unroll
    for (int o = 32; o; o >>= 1) v = fmaxf(v, __shfl_down(v, o));
    __syncthreads();
    if ((tid & 63) == 0) sb[tid >> 6] = v;
    __syncthreads();
    return fmaxf(fmaxf(sb[0], sb[1]), fmaxf(sb[2], sb[3]));
}
__device__ inline float block_sum_f(float v, float* sb, int tid) {
    #pragma unroll
    for (int o = 32; o; o >>= 1) v += __shfl_down(v, o);
    __syncthreads();
    if ((tid & 63) == 0) sb[tid >> 6] = v;
    __syncthreads();
    return sb[0] + sb[1] + sb[2] + sb[3];
}

// ---------- W1 [K][N] fp32 -> W1T bf16(RNE) [N][K] ----------
__global__ __launch_bounds__(256) void k_w1t(const float* __restrict__ W1,
                                             ushort* __restrict__ Whi) {
    __shared__ float tile[32][33];
    const int kb = blockIdx.x * 32, nb = blockIdx.y * 32;
    const int tx = threadIdx.x & 31, ty = threadIdx.x >> 5;   // ty 0..7
    #pragma unroll
    for (int i = 0; i < 4; i++)
        tile[ty + 8*i][tx] = W1[(long)(kb + ty + 8*i) * H_ + nb + tx];
    __syncthreads();
    #pragma unroll
    for (int i = 0; i < 4; i++) {
        long o = (long)(nb + ty + 8*i) * D_ + kb + tx;
        Whi[o] = (ushort)f2bf_rne(tile[tx][ty + 8*i]);
    }
}

// ---------- phase 1: BK=64 two-phase-per-tile pipelined MFMA GEMM -> e ----------
// 512 thr = 8 waves (2m x 4n), block tile 128x256, 2 LDS bufs (98 KB, 1 blk/CU).
// Per K-tile: P0 {8 ds_read kk0 | 4 gload_lds B(t+1) | 2 ldA(t+2) | bar | lgkm0 |
// 16 MFMA | bar}; P1 {8 ds_read kk1 | 2 ldA(t+2) | cvt+2 ds_write A(t+1) |
// vmcnt(4)+lgkm0 | bar | 16 MFMA | bar}. vmcnt(4) = exactly the 4 younger A-loads;
// A issue->use distance = 4 phases (covers ~900cy HBM). LDS fragment-major:
// [slab=row>>4][kc=k>>3][row&15][8] -> every frag ds_read_b128 = base+lane*16.
__global__ __launch_bounds__(512) void k_e_mfma(
    const float* __restrict__ x,
    const ushort* __restrict__ Whi,
    const float* __restrict__ b1, const float* __restrict__ W2,
    const float* __restrict__ b2, float* __restrict__ e_out)
{
    __shared__ ushort sA[2][BM * BKL];   // 16 KB each
    __shared__ ushort sB[2][H_ * BKL];   // 32 KB each
    __shared__ float  sRed[4][BM];       // 2 KB

    const int tid  = threadIdx.x;
    const int lane = tid & 63;
    const int wv   = tid >> 6;
    const int wm   = wv >> 2, wn = wv & 3;
    const int l15  = lane & 15, lg = lane >> 4;
    const long row0 = (long)blockIdx.x * BM;

    // A staging: thread -> row r=tid>>2, k-quarter aq=tid&3 (16 fp32 = 64B)
    const int ar = tid >> 2, aq = tid & 3;
    const float* aga = x + (row0 + ar) * (long)D_ + aq * 16;
    const int awo0 = (ar >> 4) * 1024 + (aq * 2) * 128 + (ar & 15) * 8;
    const int awo1 = awo0 + 128;

    // B staging: wave issues 4 gload_lds, 1KB-block L=wv*4+j; dst = L*512 ushorts
    // (linear match to layout); src lane: n=(L>>1)*16+(lane&15), kc=(L&1)*4+(lane>>4)
    const ushort* bsrc[4];
    #pragma unroll
    for (int j = 0; j < 4; j++) {
        const int L = wv * 4 + j;
        const int n  = (L >> 1) * 16 + (lane & 15);
        const int kc = (L & 1) * 4 + (lane >> 4);
        bsrc[j] = Whi + (long)n * D_ + kc * 8;
    }
    const int bb = wv * 2048;   // uniform dst base (ushorts)

    // fragment read offsets per kk-half
    int aoff[2][4], boff[2][4];
    #pragma unroll
    for (int kk = 0; kk < 2; kk++) {
        #pragma unroll
        for (int f = 0; f < 4; f++) {
            aoff[kk][f] = (wm * 4 + f) * 1024 + (kk * 4 + lg) * 128 + l15 * 8;
            boff[kk][f] = (wn * 4 + f) * 1024 + (kk * 4 + lg) * 128 + l15 * 8;
        }
    }

    f32x4 acc[4][4];
    #pragma unroll
    for (int i = 0; i < 4; i++)
        #pragma unroll
        for (int j = 0; j < 4; j++) acc[i][j] = (f32x4){0.f, 0.f, 0.f, 0.f};

    float4 Ra0, Ra1, Ra2, Ra3, Rb0, Rb1, Rb2, Rb3;

#define STAGEB(T, BUF) do { \
    _Pragma("unroll") \
    for (int j = 0; j < 4; j++) GLL(bsrc[j] + (T) * BKL, &sB[BUF][bb + j * 512]); \
} while (0)

#define WRITEA(BUF, S0, S1, S2, S3) do { \
    uint4 _u0 = make_uint4(pk2((S0).x,(S0).y), pk2((S0).z,(S0).w), \
                           pk2((S1).x,(S1).y), pk2((S1).z,(S1).w)); \
    uint4 _u1 = make_uint4(pk2((S2).x,(S2).y), pk2((S2).z,(S2).w), \
                           pk2((S3).x,(S3).y), pk2((S3).z,(S3).w)); \
    *(uint4*)&sA[BUF][awo0] = _u0; \
    *(uint4*)&sA[BUF][awo1] = _u1; \
} while (0)

#define MFMA16(AF, BF) do { \
    __builtin_amdgcn_s_setprio(1); \
    _Pragma("unroll") \
    for (int fm = 0; fm < 4; fm++) \
        _Pragma("unroll") \
        for (int fn = 0; fn < 4; fn++) \
            acc[fm][fn] = __builtin_amdgcn_mfma_f32_16x16x32_bf16((AF)[fm], (BF)[fn], acc[fm][fn], 0, 0, 0); \
    __builtin_amdgcn_s_setprio(0); \
} while (0)

#define TILE_BODY(T, C, L0, L1, L2, L3, W0, W1v, W2v, W3) do { \
    const int _tn = ((T) + 1 < NKT) ? (T) + 1 : NKT - 1; \
    const int _tp = ((T) + 2 < NKT) ? (T) + 2 : NKT - 1; \
    /* ---- P0 ---- */ \
    short8 _a0[4], _b0[4]; \
    _Pragma("unroll") \
    for (int f = 0; f < 4; f++) _b0[f] = *(const short8*)&sB[C][boff[0][f]]; \
    _Pragma("unroll") \
    for (int f = 0; f < 4; f++) _a0[f] = *(const short8*)&sA[C][aoff[0][f]]; \
    STAGEB(_tn, (C) ^ 1); \
    L0 = *(const float4*)(aga + _tp * BKL); \
    L1 = *(const float4*)(aga + _tp * BKL + 4); \
    BARRIER(); LGKM0(); \
    MFMA16(_a0, _b0); \
    BARRIER(); \
    /* ---- P1 ---- */ \
    short8 _a1[4], _b1[4]; \
    _Pragma("unroll") \
    for (int f = 0; f < 4; f++) _b1[f] = *(const short8*)&sB[C][boff[1][f]]; \
    _Pragma("unroll") \
    for (int f = 0; f < 4; f++) _a1[f] = *(const short8*)&sA[C][aoff[1][f]]; \
    L2 = *(const float4*)(aga + _tp * BKL + 8); \
    L3 = *(const float4*)(aga + _tp * BKL + 12); \
    WRITEA((C) ^ 1, W0, W1v, W2v, W3); \
    FENCEA(); BARRIER(); \
    MFMA16(_a1, _b1); \
    BARRIER(); \
} while (0)

    // prologue: A(0)->Ra, write A(0); A(1)->Rb (held); B(0),B(1) staged; drain.
    Ra0 = *(const float4*)(aga + 0);
    Ra1 = *(const float4*)(aga + 4);
    Ra2 = *(const float4*)(aga + 8);
    Ra3 = *(const float4*)(aga + 12);
    STAGEB(0, 0);
    STAGEB(1, 1);
    Rb0 = *(const float4*)(aga + BKL + 0);
    Rb1 = *(const float4*)(aga + BKL + 4);
    Rb2 = *(const float4*)(aga + BKL + 8);
    Rb3 = *(const float4*)(aga + BKL + 12);
    WRITEA(0, Ra0, Ra1, Ra2, Ra3);
    FENCE0(); BARRIER();

    // main loop: even tile uses buf0, loads->Ra, writes Rb(A(t+1));
    //            odd tile uses buf1, loads->Rb, writes Ra.
    for (int t = 0; t < NKT; t += 2) {
        TILE_BODY(t,     0, Ra0, Ra1, Ra2, Ra3, Rb0, Rb1, Rb2, Rb3);
        TILE_BODY(t + 1, 1, Rb0, Rb1, Rb2, Rb3, Ra0, Ra1, Ra2, Ra3);
    }
    FENCE0(); BARRIER();

#undef TILE_BODY
#undef MFMA16
#undef WRITEA
#undef STAGEB

    // epilogue: e partial = sum_j tanh(G+b1[j])*W2[j]; D frag: col=l15, row=lg*4+r
    float b1v[4], w2v[4];
    #pragma unroll
    for (int fn = 0; fn < 4; fn++) {
        int j = wn * 64 + fn * 16 + l15;
        b1v[fn] = b1[j]; w2v[fn] = W2[j];
    }
    #pragma unroll
    for (int fm = 0; fm < 4; fm++) {
        #pragma unroll
        for (int r = 0; r < 4; r++) {
            float s = 0.f;
            #pragma unroll
            for (int fn = 0; fn < 4; fn++)
                s += tanhf(acc[fm][fn][r] + b1v[fn]) * w2v[fn];
            s += __shfl_xor(s, 1); s += __shfl_xor(s, 2);
            s += __shfl_xor(s, 4); s += __shfl_xor(s, 8);
            if (l15 == 0) sRed[wn][wm * 64 + fm * 16 + lg * 4 + r] = s;
        }
    }
    __syncthreads();
    if (tid < BM)
        e_out[row0 + tid] = sRed[0][tid] + sRed[1][tid] + sRed[2][tid] + sRed[3][tid] + b2[0];
}

// ---------- phase 2: rank threshold; BUILD=1 -> band list, BUILD=0 -> survivor list ----------
// thread handles 16 CONSECUTIVE t (t = tid*16+i) so compaction is t-ordered.
template<int BUILD>
__global__ __launch_bounds__(256) void k_thresh(const float* __restrict__ e,
                                                int* __restrict__ counts,
                                                int* __restrict__ list,
                                                int* __restrict__ sidx,
                                                float* __restrict__ sval,
                                                int* __restrict__ scount) {
    __shared__ int   sbi[4];
    __shared__ float sbf[4];
    __shared__ int   wsum[4];
    __shared__ int   scnt;
    const int b = blockIdx.x, tid = threadIdx.x;
    const int lane = tid & 63, wid = tid >> 6;
    const float* eb = e + (long)b * T_;
    const int t0 = tid * 16;

    float fe[16]; unsigned ue[16];
    #pragma unroll
    for (int i = 0; i < 16; i += 4) {
        float4 v = *(const float4*)(eb + t0 + i);
        fe[i] = v.x; fe[i+1] = v.y; fe[i+2] = v.z; fe[i+3] = v.w;
    }
    #pragma unroll
    for (int i = 0; i < 16; i++) ue[i] = f2s(fe[i]);

    unsigned lo = 0u, hi = 0xFFFFFFFFu;
    while (lo < hi) {
        unsigned mid = lo + ((hi - lo) >> 1);
        int c = 0;
        #pragma unroll
        for (int i = 0; i < 16; i++) c += (ue[i] <= mid) ? 1 : 0;
        int total = block_sum_i(c, sbi, tid);
        if (total >= KTH + 1) hi = mid; else lo = mid + 1;
    }
    const float thr = s2f(lo);

    if (BUILD) {
        if (tid == 0) scnt = 0;
        __syncthreads();
        #pragma unroll
        for (int i = 0; i < 16; i++) {
            if (fabsf(fe[i] - thr) <= EPSB) {
                int p = atomicAdd(&scnt, 1);
                if (p < MAXBAND) list[b * MAXBAND + p] = t0 + i;
            }
        }
        __syncthreads();
        if (tid == 0) counts[b] = scnt < MAXBAND ? scnt : MAXBAND;
    } else {
        float m = -INFINITY;
        #pragma unroll
        for (int i = 0; i < 16; i++) if (fe[i] < thr) m = fmaxf(m, fe[i]);
        m = block_max_f(m, sbf, tid);
        float s = 0.f;
        #pragma unroll
        for (int i = 0; i < 16; i++) if (fe[i] < thr) s += expf(fe[i] - m);
        s = block_sum_f(s, sbf, tid);
        const float inv = 1.0f / s;

        // deterministic t-ordered compaction: block exclusive scan of counts
        int c = 0;
        #pragma unroll
        for (int i = 0; i < 16; i++) c += (fe[i] < thr) ? 1 : 0;
        int p = c;
        #pragma unroll
        for (int o = 1; o < 64; o <<= 1) {
            int y = __shfl_up(p, o);
            if (lane >= o) p += y;
        }
        if (lane == 63) wsum[wid] = p;          // wave total
        __syncthreads();
        int base = 0;
        #pragma unroll
        for (int w = 0; w < 4; w++) base += (w < wid) ? wsum[w] : 0;
        int pos = base + p - c;                 // exclusive prefix
        #pragma unroll
        for (int i = 0; i < 16; i++) {
            if (fe[i] < thr) {
                sidx[(long)b * T_ + pos] = t0 + i;
                sval[(long)b * T_ + pos] = expf(fe[i] - m) * inv;
                pos++;
            }
        }
        if (tid == 0) scount[b] = wsum[0] + wsum[1] + wsum[2] + wsum[3];
    }
}

// ---------- phase 2.5: exact fp32 recompute of band rows, RB rows share one W1 stream ----------
__global__ __launch_bounds__(256) void k_refine(const float* __restrict__ x,
        const float* __restrict__ W1, const float* __restrict__ b1,
        const float* __restrict__ W2, const float* __restrict__ b2,
        const int* __restrict__ counts, const int* __restrict__ list,
        float* __restrict__ e) {
    const int b   = blockIdx.y;
    const int blk = blockIdx.x;            // 0..15
    const int cnt = counts[b];
    const int tid = threadIdx.x;
    __shared__ float xs[RB][D_];           // 16 KB
    __shared__ float sbf[4];

    for (int g = blk * RB; g < cnt; g += 16 * RB) {
        const int nr = min(RB, cnt - g);
        for (int j = 0; j < nr; j++) {
            const int t = list[b * MAXBAND + g + j];
            *(float4*)&xs[j][tid * 4] =
                *(const float4*)&x[((long)b * T_ + t) * D_ + tid * 4];
        }
        __syncthreads();

        float a0 = 0.f, a1 = 0.f, a2 = 0.f, a3 = 0.f;
        for (int k0 = 0; k0 < D_; k0 += 4) {
            const float w0 = W1[(long)(k0 + 0) * H_ + tid];
            const float w1v = W1[(long)(k0 + 1) * H_ + tid];
            const float w2q = W1[(long)(k0 + 2) * H_ + tid];
            const float w3 = W1[(long)(k0 + 3) * H_ + tid];
            {
                float4 xv = *(const float4*)&xs[0][k0];
                a0 = fmaf(xv.x, w0, a0); a0 = fmaf(xv.y, w1v, a0);
                a0 = fmaf(xv.z, w2q, a0); a0 = fmaf(xv.w, w3, a0);
            }
            {
                float4 xv = *(const float4*)&xs[1][k0];
                a1 = fmaf(xv.x, w0, a1); a1 = fmaf(xv.y, w1v, a1);
                a1 = fmaf(xv.z, w2q, a1); a1 = fmaf(xv.w, w3, a1);
            }
            {
                float4 xv = *(const float4*)&xs[2][k0];
                a2 = fmaf(xv.x, w0, a2); a2 = fmaf(xv.y, w1v, a2);
                a2 = fmaf(xv.z, w2q, a2); a2 = fmaf(xv.w, w3, a2);
            }
            {
                float4 xv = *(const float4*)&xs[3][k0];
                a3 = fmaf(xv.x, w0, a3); a3 = fmaf(xv.y, w1v, a3);
                a3 = fmaf(xv.z, w2q, a3); a3 = fmaf(xv.w, w3, a3);
            }
        }

        float aj[RB] = {a0, a1, a2, a3};
        for (int j = 0; j < nr; j++) {
            float v = tanhf(aj[j] + b1[tid]) * W2[tid];
            float tot = block_sum_f(v, sbf, tid);
            if (tid == 0) {
                const int t = list[b * MAXBAND + g + j];
                e[(long)b * T_ + t] = tot + b2[0];
            }
            __syncthreads();
        }
        __syncthreads();
    }
}

// ---------- phase 3: dense survivor-list PV ----------
__global__ __launch_bounds__(256) void k_pv(const float* __restrict__ x,
                                            const int* __restrict__ sidx,
                                            const float* __restrict__ sval,
                                            const int* __restrict__ scount,
                                            float* __restrict__ partial) {
    const int c = blockIdx.x, b = blockIdx.y, tid = threadIdx.x;
    const int cnt = scount[b];
    const int len = (cnt + SC - 1) / SC;       // <= 32 (cnt <= 2048)
    const int k0 = c * len;
    const int nl = min(len, cnt - k0);
    __shared__ int   si[32];
    __shared__ float sv[32];
    if (tid < nl) {
        si[tid] = sidx[(long)b * T_ + k0 + tid];
        sv[tid] = sval[(long)b * T_ + k0 + tid];
    }
    __syncthreads();

    float4 acc = {0.f, 0.f, 0.f, 0.f};
    const float* xb = x + (long)b * T_ * D_ + tid * 4;
    #pragma unroll 4
    for (int k = 0; k < nl; k++) {
        const float w = sv[k];
        float4 v = *(const float4*)(xb + (long)si[k] * D_);
        acc.x = fmaf(w, v.x, acc.x);
        acc.y = fmaf(w, v.y, acc.y);
        acc.z = fmaf(w, v.z, acc.z);
        acc.w = fmaf(w, v.w, acc.w);
    }
    *(float4*)&partial[(((long)b * SC) + c) * D_ + tid * 4] = acc;
}

// ---------- phase 4 ----------
__global__ __launch_bounds__(256) void k_red(const float* __restrict__ partial,
                                             float* __restrict__ out) {
    const int b = blockIdx.x, tid = threadIdx.x;
    float4 acc = {0.f, 0.f, 0.f, 0.f};
    #pragma unroll
    for (int c = 0; c < SC; c++) {
        float4 v = *(const float4*)&partial[(((long)b * SC) + c) * D_ + tid * 4];
        acc.x += v.x; acc.y += v.y; acc.z += v.z; acc.w += v.w;
    }
    *(float4*)&out[(long)b * D_ + tid * 4] = acc;
}

extern "C" void kernel_launch(void* const* d_in, const int* in_sizes, int n_in,
                              void* d_out, int out_size, void* d_ws, size_t ws_size,
                              hipStream_t stream) {
    const float* x  = (const float*)d_in[0];
    const float* W1 = (const float*)d_in[1];
    const float* b1 = (const float*)d_in[2];
    const float* W2 = (const float*)d_in[3];
    const float* b2 = (const float*)d_in[4];
    float* out = (float*)d_out;

    char* ws = (char*)d_ws;
    float* e       = (float*)ws;  ws += (size_t)B_ * T_ * 4;
    int*   sidx    = (int*)ws;    ws += (size_t)B_ * T_ * 4;
    float* sval    = (float*)ws;  ws += (size_t)B_ * T_ * 4;
    float* partial = (float*)ws;  ws += (size_t)B_ * SC * D_ * 4;
    ushort* Whi    = (ushort*)ws; ws += (size_t)H_ * D_ * 2;
    int* counts    = (int*)ws;    ws += 128;
    int* scountp   = (int*)ws;    ws += 128;
    int* list      = (int*)ws;

    k_w1t<<<dim3(D_ / 32, H_ / 32), 256, 0, stream>>>(W1, Whi);
    k_e_mfma<<<(B_ * T_) / BM, 512, 0, stream>>>(x, Whi, b1, W2, b2, e);
    k_thresh<1><<<B_, 256, 0, stream>>>(e, counts, list, sidx, sval, scountp);
    k_refine<<<dim3(16, B_), 256, 0, stream>>>(x, W1, b1, W2, b2, counts, list, e);
    k_thresh<0><<<B_, 256, 0, stream>>>(e, counts, list, sidx, sval, scountp);
    k_pv<<<dim3(SC, B_), 256, 0, stream>>>(x, sidx, sval, scountp, partial);
    k_red<<<B_, 256, 0, stream>>>(partial, out);
}